// Round 9
// baseline (311.817 us; speedup 1.0000x reference)
//
#include <hip/hip_runtime.h>
#include <hip/hip_bf16.h>

#define N_NODES 100000
#define N_EDGES 1600000
#define NFEAT   128
#define NGRAPH  256
#define NACT    32
#define ECAP    64
#define OVF_CAP 8192

// ---- two-pass edge partition ----
#define BUCK_SHIFT 9
#define BUCK_NODES 512
#define NBUCK ((N_NODES + BUCK_NODES - 1) / BUCK_NODES)   // 196
#define SEGCAP 10240          // mean 8192, +22 sigma
#define CHUNK 2048            // R9: halved (791->782 blocks x2 parallelism,
                              // half the per-block serial critical path)
#define NBLK1 ((N_EDGES + CHUNK - 1) / CHUNK)             // 782
#define WT2BLK 64             // W2 transpose blocks (16384 elems / 256)
#define BIN_NODES 128         // pass-2 nodes per block
#define NBLK2 ((N_NODES + BIN_NODES - 1) / BIN_NODES)     // 782
#define GB ((N_NODES + 63) / 64)                          // 1563 gemm blocks
#define LDSROW 136            // ushort row stride: 16B-aligned, uniform banks

typedef __attribute__((ext_vector_type(8))) short bf16x8;
typedef __attribute__((ext_vector_type(4))) float f32x4;

__device__ inline unsigned short f2bf(float f) {
  __hip_bfloat16 b = __float2bfloat16(f);
  return *reinterpret_cast<unsigned short*>(&b);
}
__device__ inline float2 bfu2f(unsigned u) {
  __hip_bfloat162 t = *reinterpret_cast<__hip_bfloat162*>(&u);
  return __bfloat1622float2(t);
}

// ---- launch 1: edgepart [0,NBLK1) UNION wt2 transpose [NBLK1,NBLK1+64)
//                UNION layer-1 GEMM (rest).
// gemm1 depends only on x/W1; its 1563 blocks backfill CUs left idle by the
// barrier-heavy edgepart blocks. gemm1 self-stages W1^T(bf16) in LDS.
// Shared-memory is one aliased arena sized for gemm1's 34.8KB wtile.
__global__ __launch_bounds__(256) void edgepart_wt_gemm1_kernel(
    const int* __restrict__ src, const int* __restrict__ dst,
    int* __restrict__ bucket_cursor, int2* __restrict__ seg,
    int* __restrict__ cnt, int* __restrict__ ovf_cnt, int* __restrict__ ovf,
    const float* __restrict__ W1, const float* __restrict__ W2,
    unsigned short* __restrict__ Wt2,
    const float* __restrict__ x, unsigned short* __restrict__ C) {
  __shared__ __align__(16) char smem[36928];
  int tid = threadIdx.x;

  if (blockIdx.x >= NBLK1 + WT2BLK) {         // ---- gemm1: C(bf16) = x @ W1 ----
    unsigned short* wtile = (unsigned short*)smem;   // [128][136] bf16 W1^T
    for (int i = tid; i < NFEAT * NFEAT; i += 256) {
      int k = i >> 7, n = i & 127;
      wtile[n * LDSROW + k] = f2bf(W1[i]);    // W1[k][n] -> wtile[n][k]
    }
    __syncthreads();

    int bid = blockIdx.x - NBLK1 - WT2BLK;
    int wave = tid >> 6, lane = tid & 63;
    int q = lane >> 4, r = lane & 15;
    int m0 = bid * 64 + wave * 16;
    int arow = m0 + r; if (arow > N_NODES - 1) arow = N_NODES - 1;
    const float* Arow = x + (size_t)arow * NFEAT;

    f32x4 acc[8];
    #pragma unroll
    for (int t = 0; t < 8; ++t) acc[t] = (f32x4){0.f, 0.f, 0.f, 0.f};

    #pragma unroll
    for (int s = 0; s < 4; ++s) {
      int k0 = s * 32 + q * 8;
      float4 a0 = *(const float4*)(Arow + k0);
      float4 a1 = *(const float4*)(Arow + k0 + 4);
      bf16x8 xf;
      xf[0] = (short)f2bf(a0.x); xf[1] = (short)f2bf(a0.y);
      xf[2] = (short)f2bf(a0.z); xf[3] = (short)f2bf(a0.w);
      xf[4] = (short)f2bf(a1.x); xf[5] = (short)f2bf(a1.y);
      xf[6] = (short)f2bf(a1.z); xf[7] = (short)f2bf(a1.w);
      #pragma unroll
      for (int t = 0; t < 8; ++t) {
        bf16x8 wf = *(const bf16x8*)(wtile + (size_t)(t * 16 + r) * LDSROW + k0);
        acc[t] = __builtin_amdgcn_mfma_f32_16x16x32_bf16(wf, xf, acc[t], 0, 0, 0);
      }
    }
    int node = m0 + r;
    if (node < N_NODES) {
      uint2* Crow = (uint2*)(C + (size_t)node * NFEAT);
      #pragma unroll
      for (int t = 0; t < 8; ++t) {
        uint2 v;
        v.x = ((unsigned)f2bf(acc[t][1]) << 16) | f2bf(acc[t][0]);
        v.y = ((unsigned)f2bf(acc[t][3]) << 16) | f2bf(acc[t][2]);
        Crow[t * 4 + q] = v;    // features [t*16+q*4, +4)
      }
    }
    return;
  }

  if (blockIdx.x >= NBLK1) {                  // ---- Wt2 transpose part ----
    int i = (blockIdx.x - NBLK1) * 256 + tid; // 16384 weight elems
    int n = i >> 7, k = i & 127;
    Wt2[n * NFEAT + k] = f2bf(W2[k * NFEAT + n]);
    return;
  }

  // ---- edgepart part ----
  int2* stage = (int2*)smem;                  // CHUNK*8 = 16 KB
  int* hist   = (int*)(smem + CHUNK * 8);
  int* offs   = hist + NBUCK;
  int* cursor = offs + NBUCK;
  int* gbase  = cursor + NBUCK;
  int* sc     = gbase + NBUCK;                // 256 ints; total 20.5 KB

  int e0 = blockIdx.x * CHUNK;
  int m = N_EDGES - e0; if (m > CHUNK) m = CHUNK;

  for (int i = tid; i < NBUCK; i += 256) hist[i] = 0;
  __syncthreads();

  for (int i = tid; i < m; i += 256)
    atomicAdd(&hist[dst[e0 + i] >> BUCK_SHIFT], 1);
  __syncthreads();

  sc[tid] = (tid < NBUCK) ? hist[tid] : 0;
  __syncthreads();
  for (int ofs = 1; ofs < 256; ofs <<= 1) {
    int t = (tid >= ofs) ? sc[tid - ofs] : 0;
    __syncthreads();
    sc[tid] += t;
    __syncthreads();
  }
  if (tid < NBUCK) {
    int o = tid ? sc[tid - 1] : 0;
    offs[tid] = o;
    cursor[tid] = o;
    gbase[tid] = hist[tid] ? atomicAdd(&bucket_cursor[tid], hist[tid]) : 0;
  }
  __syncthreads();

  for (int i = tid; i < m; i += 256) {
    int2 p = make_int2(src[e0 + i], dst[e0 + i]);
    int pos = atomicAdd(&cursor[p.y >> BUCK_SHIFT], 1);
    stage[pos] = p;
  }
  __syncthreads();

  for (int i = tid; i < m; i += 256) {
    int2 p = stage[i];
    int bd = p.y >> BUCK_SHIFT;
    int gpos = gbase[bd] + (i - offs[bd]);
    if (gpos < SEGCAP) {
      seg[(size_t)bd * SEGCAP + gpos] = p;
    } else {                                // ~never: count + defer to agg ovf fixup
      atomicAdd(&cnt[p.y], 1);
      int o = atomicAdd(ovf_cnt, 1);
      if (o < OVF_CAP) { ovf[2 * o] = p.x; ovf[2 * o + 1] = p.y; }
    }
  }
}

// ---- launch 2: binbuild only ----
__global__ __launch_bounds__(256) void binbuild_kernel(const int2* __restrict__ seg,
                                                       const int* __restrict__ bucket_cursor,
                                                       int* __restrict__ cnt,
                                                       float* __restrict__ dinv,
                                                       int* __restrict__ elist,
                                                       int* __restrict__ ovf_cnt,
                                                       int* __restrict__ ovf) {
  __shared__ int lcnt[BIN_NODES];
  __shared__ int lel[BIN_NODES * ECAP];     // 32 KB
  int tid = threadIdx.x;

  int n0 = blockIdx.x * BIN_NODES;
  int pb = n0 >> BUCK_SHIFT;
  if (tid < BIN_NODES) lcnt[tid] = 0;
  __syncthreads();
  int m = bucket_cursor[pb]; if (m > SEGCAP) m = SEGCAP;
  const int2* s = seg + (size_t)pb * SEGCAP;
  for (int e = tid; e < m; e += 256) {
    int2 p = s[e];
    unsigned ln = (unsigned)(p.y - n0);
    if (ln < (unsigned)BIN_NODES) {
      int pos = atomicAdd(&lcnt[ln], 1);
      if (pos < ECAP) {
        lel[(ln << 6) + pos] = p.x;
      } else {                              // high-degree node: agg ovf fixup
        int o = atomicAdd(ovf_cnt, 1);
        if (o < OVF_CAP) { ovf[2 * o] = p.x; ovf[2 * o + 1] = p.y; }
      }
    }
  }
  __syncthreads();
  if (tid < BIN_NODES) {
    int n = n0 + tid;
    if (n < N_NODES) {
      int tot = cnt[n] + lcnt[tid];          // cnt[n]: pass-1 ovf edges only
      cnt[n] = tot;                          // safe: block owns node range
      dinv[n] = rsqrtf((float)tot + 1.0f);   // fused dinv
    }
  }
  int4* gel = (int4*)(elist + (size_t)n0 * ECAP);
  const int4* lel4 = (const int4*)lel;
  for (int i = tid; i < BIN_NODES * ECAP / 4; i += 256) gel[i] = lel4[i];
}

// ---------------- launch 3: layer-1 aggregation FUSED with layer-2 GEMM ------
// (R5 form: weighted gather over H1; epilogue writes P2 = dinv*(A1@W2) so
// layer-2's aggregation is unweighted.)
__global__ __launch_bounds__(512) void agg_gemm_kernel(const uint2* __restrict__ h2,
                                                       const int* __restrict__ elist,
                                                       const int* __restrict__ cnt,
                                                       const float* __restrict__ dinv,
                                                       const float* __restrict__ bias,
                                                       const int* __restrict__ ovf_cnt,
                                                       const int* __restrict__ ovf,
                                                       const unsigned short* __restrict__ Wt2,
                                                       unsigned short* __restrict__ H2) {
  __shared__ __align__(16) unsigned short hloc[16 * LDSROW];  // 4.25 KB
  int tid = threadIdx.x;
  int lane = tid & 63;
  int lw = tid >> 6;                         // local wave 0..7
  int hl = lane & 31;
  int n0 = blockIdx.x * 16;
  int nloc = lw * 2 + (lane >> 5);
  int n = n0 + nloc;                         // grid exact: 6250*16 == N_NODES

  float dn = dinv[n];
  int c = cnt[n]; c = (c > ECAP) ? ECAP : c;
  const int* el = elist + (size_t)n * ECAP;

  int   s0 = (hl < c)      ? el[hl]      : n;
  float w0 = (hl < c)      ? dinv[s0] * dn : 0.f;
  int   s1 = (hl + 32 < c) ? el[hl + 32] : n;
  float w1 = (hl + 32 < c) ? dinv[s1] * dn : 0.f;

  int cA = __shfl(c, 0), cB = __shfl(c, 32);
  int cmax = cA > cB ? cA : cB;

  uint2 hv = h2[(size_t)n * 32 + hl];
  float2 vlo = bfu2f(hv.x), vhi = bfu2f(hv.y);
  float sw = dn * dn;
  float a0 = sw * vlo.x, a1 = sw * vlo.y, a2 = sw * vhi.x, a3 = sw * vhi.y;

  int e1 = cmax < 32 ? cmax : 32;
  e1 = (e1 + 7) & ~7;                        // pad: no scalar tail
  for (int j = 0; j < e1; j += 8) {
    uint2 pv[8]; float w[8];
    #pragma unroll
    for (int u = 0; u < 8; ++u) {
      int s = __shfl(s0, j + u, 32);
      w[u] = __shfl(w0, j + u, 32);
      pv[u] = h2[(size_t)s * 32 + hl];
    }
    #pragma unroll
    for (int u = 0; u < 8; ++u) {
      float2 lo = bfu2f(pv[u].x), hi = bfu2f(pv[u].y);
      a0 = fmaf(w[u], lo.x, a0); a1 = fmaf(w[u], lo.y, a1);
      a2 = fmaf(w[u], hi.x, a2); a3 = fmaf(w[u], hi.y, a3);
    }
  }
  if (cmax > 32) {
    int e2 = ((cmax - 32) + 7) & ~7;         // <= 32 since c clamped to ECAP
    for (int j = 0; j < e2; j += 8) {
      uint2 pv[8]; float w[8];
      #pragma unroll
      for (int u = 0; u < 8; ++u) {
        int s = __shfl(s1, j + u, 32);
        w[u] = __shfl(w1, j + u, 32);
        pv[u] = h2[(size_t)s * 32 + hl];
      }
      #pragma unroll
      for (int u = 0; u < 8; ++u) {
        float2 lo = bfu2f(pv[u].x), hi = bfu2f(pv[u].y);
        a0 = fmaf(w[u], lo.x, a0); a1 = fmaf(w[u], lo.y, a1);
        a2 = fmaf(w[u], hi.x, a2); a3 = fmaf(w[u], hi.y, a3);
      }
    }
  }

  int m = *ovf_cnt; if (m > OVF_CAP) m = OVF_CAP;
  for (int p = 0; p < m; ++p) {
    int s = ovf[2 * p], d = ovf[2 * p + 1];
    if (d == n) {
      float w = dinv[s] * dn;
      uint2 pv = h2[(size_t)s * 32 + hl];
      float2 lo = bfu2f(pv.x), hi = bfu2f(pv.y);
      a0 = fmaf(w, lo.x, a0); a1 = fmaf(w, lo.y, a1);
      a2 = fmaf(w, hi.x, a2); a3 = fmaf(w, hi.y, a3);
    }
  }

  float4 b4 = ((const float4*)bias)[hl];
  uint2 v;
  v.x = ((unsigned)f2bf(fmaxf(a1 + b4.y, 0.f)) << 16) | f2bf(fmaxf(a0 + b4.x, 0.f));
  v.y = ((unsigned)f2bf(fmaxf(a3 + b4.w, 0.f)) << 16) | f2bf(fmaxf(a2 + b4.z, 0.f));
  *(uint2*)(&hloc[nloc * LDSROW + hl * 4]) = v;
  __syncthreads();

  // ---- phase 2: gemm2 tile. wave lw -> output feats [lw*16, lw*16+16) ----
  int q = lane >> 4, r = lane & 15;
  int node = n0 + r;
  float dvr = dinv[node];                    // for P2 pre-scale (load early)
  f32x4 acc = (f32x4){0.f, 0.f, 0.f, 0.f};
  #pragma unroll
  for (int s = 0; s < 4; ++s) {
    int k0 = s * 32 + q * 8;
    bf16x8 xf = *(const bf16x8*)(&hloc[r * LDSROW + k0]);
    bf16x8 wf = *(const bf16x8*)(Wt2 + (size_t)(lw * 16 + r) * NFEAT + k0);
    acc = __builtin_amdgcn_mfma_f32_16x16x32_bf16(wf, xf, acc, 0, 0, 0);
  }
  uint2* Crow = (uint2*)(H2 + (size_t)node * NFEAT);
  uint2 o;
  o.x = ((unsigned)f2bf(dvr * acc[1]) << 16) | f2bf(dvr * acc[0]);
  o.y = ((unsigned)f2bf(dvr * acc[3]) << 16) | f2bf(dvr * acc[2]);
  Crow[lw * 4 + q] = o;                      // feats [lw*16+q*4, +4)
}

// ---------------- launch 4: layer-2 aggregation + FUSED POOL ----------------
// (R5 form: H2 holds PRE-SCALED rows P2 -> unweighted full-row gather.)
__global__ __launch_bounds__(256) void agg_pool_kernel(const uint2* __restrict__ h2,
                                                       const int* __restrict__ elist,
                                                       const int* __restrict__ cnt,
                                                       const float* __restrict__ dinv,
                                                       const float* __restrict__ bias,
                                                       const int* __restrict__ ovf_cnt,
                                                       const int* __restrict__ ovf,
                                                       const int* __restrict__ batch,
                                                       float* __restrict__ gsum) {
  __shared__ float lds[8][NFEAT];            // 4 KB
  int tid = threadIdx.x;
  int wid = (blockIdx.x * 256 + tid) >> 6;
  int lane = tid & 63;
  int hl = lane & 31;
  int n = wid * 2 + (lane >> 5);             // grid covers exactly N_NODES
  int n0 = blockIdx.x * 8;

  float dn = dinv[n];
  int c = cnt[n]; c = (c > ECAP) ? ECAP : c;
  const int* el = elist + (size_t)n * ECAP;

  int s0 = (hl < c)      ? el[hl]      : n;
  int s1 = (hl + 32 < c) ? el[hl + 32] : n;

  int cA = __shfl(c, 0), cB = __shfl(c, 32);
  int cmax = cA > cB ? cA : cB;

  uint2 hv = h2[(size_t)n * 32 + hl];        // self row P2[n], weight 1
  float2 vlo = bfu2f(hv.x), vhi = bfu2f(hv.y);
  float a0 = vlo.x, a1 = vlo.y, a2 = vhi.x, a3 = vhi.y;

  int e1 = cmax < 32 ? cmax : 32;
  e1 = (e1 + 7) & ~7;                        // pad: no scalar tail
  for (int j = 0; j < e1; j += 8) {
    uint2 pv[8];
    #pragma unroll
    for (int u = 0; u < 8; ++u) {
      int s = __shfl(s0, j + u, 32);
      pv[u] = h2[(size_t)s * 32 + hl];
    }
    #pragma unroll
    for (int u = 0; u < 8; ++u) {
      if (j + u < c) {                       // mask padding (c uniform/half-wave)
        float2 lo = bfu2f(pv[u].x), hi = bfu2f(pv[u].y);
        a0 += lo.x; a1 += lo.y; a2 += hi.x; a3 += hi.y;
      }
    }
  }
  if (cmax > 32) {
    int e2 = 32 + (((cmax - 32) + 7) & ~7);
    for (int j = 32; j < e2; j += 8) {
      uint2 pv[8];
      #pragma unroll
      for (int u = 0; u < 8; ++u) {
        int s = __shfl(s1, j - 32 + u, 32);
        pv[u] = h2[(size_t)s * 32 + hl];
      }
      #pragma unroll
      for (int u = 0; u < 8; ++u) {
        if (j + u < c) {
          float2 lo = bfu2f(pv[u].x), hi = bfu2f(pv[u].y);
          a0 += lo.x; a1 += lo.y; a2 += hi.x; a3 += hi.y;
        }
      }
    }
  }

  int m = *ovf_cnt; if (m > OVF_CAP) m = OVF_CAP;
  for (int p = 0; p < m; ++p) {
    int s = ovf[2 * p], d = ovf[2 * p + 1];
    if (d == n) {
      uint2 pv = h2[(size_t)s * 32 + hl];
      float2 lo = bfu2f(pv.x), hi = bfu2f(pv.y);
      a0 += lo.x; a1 += lo.y; a2 += hi.x; a3 += hi.y;
    }
  }

  float4 b4 = ((const float4*)bias)[hl];
  int nloc = n - n0;
  lds[nloc][hl * 4 + 0] = fmaxf(fmaf(dn, a0, b4.x), 0.f);
  lds[nloc][hl * 4 + 1] = fmaxf(fmaf(dn, a1, b4.y), 0.f);
  lds[nloc][hl * 4 + 2] = fmaxf(fmaf(dn, a2, b4.z), 0.f);
  lds[nloc][hl * 4 + 3] = fmaxf(fmaf(dn, a3, b4.w), 0.f);
  __syncthreads();

  if (tid < NFEAT) {                         // thread t = feature t
    float sum = 0.f;
    int cur = batch[n0];
    #pragma unroll
    for (int i = 0; i < 8; ++i) {
      int b = batch[n0 + i];
      if (b != cur) {
        atomicAdd(&gsum[cur * NFEAT + tid], sum);
        sum = 0.f; cur = b;
      }
      sum += lds[i][tid];
    }
    atomicAdd(&gsum[cur * NFEAT + tid], sum);
  }
}

// ---------------- MLP head (graph-count binary search fused in) ----------------
__global__ __launch_bounds__(128) void mlp_kernel(const float* __restrict__ gsum,
                                                  const int* __restrict__ batch,
                                                  const float* __restrict__ Wl1,
                                                  const float* __restrict__ bl1,
                                                  const float* __restrict__ Wl2,
                                                  const float* __restrict__ bl2,
                                                  float* __restrict__ out) {
  __shared__ float gr[NFEAT];
  __shared__ float t1[NFEAT];
  __shared__ float sinv;
  int g = blockIdx.x, t = threadIdx.x;
  if (t == 0) {
    int lo = 0, hi = N_NODES;
    while (lo < hi) { int mid = (lo + hi) >> 1; if (batch[mid] < g) lo = mid + 1; else hi = mid; }
    int lo2 = lo, hi2 = N_NODES;
    while (lo2 < hi2) { int mid = (lo2 + hi2) >> 1; if (batch[mid] < g + 1) lo2 = mid + 1; else hi2 = mid; }
    sinv = 1.0f / fmaxf((float)(lo2 - lo), 1.0f);
  }
  __syncthreads();
  gr[t] = gsum[g * NFEAT + t] * sinv;
  __syncthreads();
  float acc = bl1[t];
  for (int k = 0; k < NFEAT; ++k) acc = fmaf(gr[k], Wl1[k * NFEAT + t], acc);
  t1[t] = fmaxf(acc, 0.f);
  __syncthreads();
  if (t < NACT) {
    float a2 = bl2[t];
    for (int k = 0; k < NFEAT; ++k) a2 = fmaf(t1[k], Wl2[k * NACT + t], a2);
    out[g * NACT + t] = a2;
  }
}

extern "C" void kernel_launch(void* const* d_in, const int* in_sizes, int n_in,
                              void* d_out, int out_size, void* d_ws, size_t ws_size,
                              hipStream_t stream) {
  const float* x    = (const float*)d_in[0];
  const int*   ei   = (const int*)d_in[1];
  const int*   batch= (const int*)d_in[2];
  const float* W1   = (const float*)d_in[3];
  const float* b1   = (const float*)d_in[4];
  const float* W2   = (const float*)d_in[5];
  const float* b2   = (const float*)d_in[6];
  const float* Wl1  = (const float*)d_in[7];
  const float* bl1  = (const float*)d_in[8];
  const float* Wl2  = (const float*)d_in[9];
  const float* bl2  = (const float*)d_in[10];
  float* out = (float*)d_out;

  const int* srcp = ei;            // edge_index[0]
  const int* dstp = ei + N_EDGES;  // edge_index[1]

  char* base = (char*)d_ws;
  size_t off = 0;
  auto alloc = [&](size_t bytes) -> void* {
    void* p = base + off;
    off += (bytes + 511) & ~(size_t)511;
    return p;
  };
  int*   cnt     = (int*)alloc((size_t)N_NODES * 4);
  int*   ovfc    = (int*)alloc(4);
  float* gsum    = (float*)alloc((size_t)NGRAPH * NFEAT * 4);
  int*   bucket_cursor = (int*)alloc((size_t)NBUCK * 4);
  size_t zspan   = off;  // everything above must start zeroed
  float* dinv    = (float*)alloc((size_t)N_NODES * 4);
  int*   elist   = (int*)alloc((size_t)NBLK2 * BIN_NODES * ECAP * 4); // padded
  int*   ovf     = (int*)alloc((size_t)OVF_CAP * 2 * 4);
  int2*  seg     = (int2*)alloc((size_t)NBUCK * SEGCAP * 8);          // 16 MB
  unsigned short* Wt2 = (unsigned short*)alloc((size_t)NFEAT * NFEAT * 2);
  unsigned short* H1 = (unsigned short*)alloc((size_t)N_NODES * NFEAT * 2); // bf16 h1W1
  unsigned short* H2 = (unsigned short*)alloc((size_t)N_NODES * NFEAT * 2); // bf16 P2

  hipMemsetAsync(d_ws, 0, zspan, stream);

  const int AB = (N_NODES + 7) / 8;       // 12500 agg_pool blocks (8 nodes/block)
  const int FB = N_NODES / 16;            // 6250 fused agg+gemm blocks (16 nodes)

  // L1: edge partition UNION Wt2 transpose UNION layer-1 GEMM (all independent)
  edgepart_wt_gemm1_kernel<<<NBLK1 + WT2BLK + GB, 256, 0, stream>>>(
      srcp, dstp, bucket_cursor, seg, cnt, ovfc, ovf, W1, W2, Wt2, x, H1);
  // L2: elist build (dep on L1 edgepart)
  binbuild_kernel<<<NBLK2, 256, 0, stream>>>(
      seg, bucket_cursor, cnt, dinv, elist, ovfc, ovf);
  // L3: layer-1 aggregation (weighted) FUSED with layer-2 GEMM (P2 pre-scale)
  agg_gemm_kernel<<<FB, 512, 0, stream>>>((const uint2*)H1, elist, cnt, dinv, b1,
                                          ovfc, ovf, Wt2, H2);
  // L4: layer-2 aggregation (unweighted, pre-scaled) + fused pool
  agg_pool_kernel<<<AB, 256, 0, stream>>>((const uint2*)H2, elist, cnt, dinv, b2,
                                          ovfc, ovf, batch, gsum);
  // L5: head
  mlp_kernel<<<NGRAPH, 128, 0, stream>>>(gsum, batch, Wl1, bl1, Wl2, bl2, out);
}

// Round 10
// 260.311 us; speedup vs baseline: 1.1979x; 1.1979x over previous
//
#include <hip/hip_runtime.h>
#include <hip/hip_bf16.h>

#define N_NODES 100000
#define N_EDGES 1600000
#define NFEAT   128
#define NGRAPH  256
#define NACT    32
#define ECAP    64
#define OVF_CAP 8192

// ---- two-pass edge partition ----
#define BUCK_SHIFT 9
#define BUCK_NODES 512
#define NBUCK ((N_NODES + BUCK_NODES - 1) / BUCK_NODES)   // 196
#define SEGCAP 10240          // mean 8192, +22 sigma
#define CHUNK 4096            // R10: reverted to 4096 (R9's 2048 was +5.7us)
#define NBLK1 ((N_EDGES + CHUNK - 1) / CHUNK)             // 391
#define WT2BLK 64             // W2 transpose blocks (16384 elems / 256)
#define BIN_NODES 128         // pass-2 nodes per block
#define NBLK2 ((N_NODES + BIN_NODES - 1) / BIN_NODES)     // 782
#define GB ((N_NODES + 63) / 64)                          // 1563 gemm blocks
#define LDSROW 136            // ushort row stride: 16B-aligned, uniform banks

typedef __attribute__((ext_vector_type(8))) short bf16x8;
typedef __attribute__((ext_vector_type(4))) float f32x4;
typedef __attribute__((ext_vector_type(2))) float f32x2;

__device__ inline unsigned short f2bf(float f) {
  __hip_bfloat16 b = __float2bfloat16(f);
  return *reinterpret_cast<unsigned short*>(&b);
}

// ---- fp8 e4m3fn helpers (R10): rows stored as fp8, 4 feats per uint ----
// HW path: gfx950 v_cvt_pk_f32_fp8 / v_cvt_pk_fp8_f32 (OCP e4m3fn).
// Fallback: bit-exact manual e4m3fn (decode multiply-trick handles denormals).
__device__ inline void fp8x4_to_f32(unsigned v, float f[4]) {
#if __has_builtin(__builtin_amdgcn_cvt_pk_f32_fp8)
  f32x2 lo = __builtin_amdgcn_cvt_pk_f32_fp8((int)v, false);
  f32x2 hi = __builtin_amdgcn_cvt_pk_f32_fp8((int)v, true);
  f[0] = lo[0]; f[1] = lo[1]; f[2] = hi[0]; f[3] = hi[1];
#else
  #pragma unroll
  for (int i = 0; i < 4; ++i) {
    unsigned b = (v >> (8 * i)) & 0xffu;
    unsigned bits = ((b << 20) & 0x07f00000u) | ((b << 24) & 0x80000000u);
    f[i] = __uint_as_float(bits) * 1.329227995784916e36f;   // x 2^120
  }
#endif
}

__device__ inline unsigned f2fp8_1(float x) {      // manual e4m3fn, round-half-up
  float a = fabsf(x);
  unsigned sg = (__float_as_uint(x) >> 24) & 0x80u;
  if (!(a < 448.f)) return sg | 0x7Eu;             // clamp to 448
  if (a < 0.015625f) {                             // < 2^-6: denormal (m=8 -> e1m0)
    unsigned m = (unsigned)fmaf(a, 512.f, 0.5f);
    return sg | m;
  }
  unsigned b = __float_as_uint(a) + 0x00080000u;   // round at 3-bit mantissa
  unsigned e = (b >> 23) - 120u;
  if (e > 15u) return sg | 0x7Eu;
  return sg | (e << 3) | ((b >> 20) & 7u);
}

__device__ inline unsigned f32x4_to_fp8(float f0, float f1, float f2, float f3) {
#if __has_builtin(__builtin_amdgcn_cvt_pk_fp8_f32)
  int v = 0;
  v = __builtin_amdgcn_cvt_pk_fp8_f32(f0, f1, v, false);
  v = __builtin_amdgcn_cvt_pk_fp8_f32(f2, f3, v, true);
  return (unsigned)v;
#else
  return f2fp8_1(f0) | (f2fp8_1(f1) << 8) | (f2fp8_1(f2) << 16) | (f2fp8_1(f3) << 24);
#endif
}

// ---- launch 1: edgepart [0,NBLK1) UNION wt2 transpose UNION layer-1 GEMM ----
// gemm1 depends only on x/W1; its 1563 blocks backfill CUs left idle by the
// barrier-heavy edgepart blocks. gemm1 self-stages W1^T(bf16) in LDS.
// R10: gemm1 writes H1 as fp8 (row = 128B = one cache line).
__global__ __launch_bounds__(256) void edgepart_wt_gemm1_kernel(
    const int* __restrict__ src, const int* __restrict__ dst,
    int* __restrict__ bucket_cursor, int2* __restrict__ seg,
    int* __restrict__ cnt, int* __restrict__ ovf_cnt, int* __restrict__ ovf,
    const float* __restrict__ W1, const float* __restrict__ W2,
    unsigned short* __restrict__ Wt2,
    const float* __restrict__ x, unsigned* __restrict__ C) {
  __shared__ __align__(16) char smem[36928];
  int tid = threadIdx.x;

  if (blockIdx.x >= NBLK1 + WT2BLK) {         // ---- gemm1: C(fp8) = x @ W1 ----
    unsigned short* wtile = (unsigned short*)smem;   // [128][136] bf16 W1^T
    for (int i = tid; i < NFEAT * NFEAT; i += 256) {
      int k = i >> 7, n = i & 127;
      wtile[n * LDSROW + k] = f2bf(W1[i]);    // W1[k][n] -> wtile[n][k]
    }
    __syncthreads();

    int bid = blockIdx.x - NBLK1 - WT2BLK;
    int wave = tid >> 6, lane = tid & 63;
    int q = lane >> 4, r = lane & 15;
    int m0 = bid * 64 + wave * 16;
    int arow = m0 + r; if (arow > N_NODES - 1) arow = N_NODES - 1;
    const float* Arow = x + (size_t)arow * NFEAT;

    f32x4 acc[8];
    #pragma unroll
    for (int t = 0; t < 8; ++t) acc[t] = (f32x4){0.f, 0.f, 0.f, 0.f};

    #pragma unroll
    for (int s = 0; s < 4; ++s) {
      int k0 = s * 32 + q * 8;
      float4 a0 = *(const float4*)(Arow + k0);
      float4 a1 = *(const float4*)(Arow + k0 + 4);
      bf16x8 xf;
      xf[0] = (short)f2bf(a0.x); xf[1] = (short)f2bf(a0.y);
      xf[2] = (short)f2bf(a0.z); xf[3] = (short)f2bf(a0.w);
      xf[4] = (short)f2bf(a1.x); xf[5] = (short)f2bf(a1.y);
      xf[6] = (short)f2bf(a1.z); xf[7] = (short)f2bf(a1.w);
      #pragma unroll
      for (int t = 0; t < 8; ++t) {
        bf16x8 wf = *(const bf16x8*)(wtile + (size_t)(t * 16 + r) * LDSROW + k0);
        acc[t] = __builtin_amdgcn_mfma_f32_16x16x32_bf16(wf, xf, acc[t], 0, 0, 0);
      }
    }
    int node = m0 + r;
    if (node < N_NODES) {
      unsigned* Crow = C + (size_t)node * 32;
      #pragma unroll
      for (int t = 0; t < 8; ++t)            // feats [t*16+q*4, +4) as 4x fp8
        Crow[t * 4 + q] = f32x4_to_fp8(acc[t][0], acc[t][1], acc[t][2], acc[t][3]);
    }
    return;
  }

  if (blockIdx.x >= NBLK1) {                  // ---- Wt2 transpose part ----
    int i = (blockIdx.x - NBLK1) * 256 + tid; // 16384 weight elems
    int n = i >> 7, k = i & 127;
    Wt2[n * NFEAT + k] = f2bf(W2[k * NFEAT + n]);
    return;
  }

  // ---- edgepart part ----
  int2* stage = (int2*)smem;                  // 32 KB
  int* hist   = (int*)(smem + 32768);
  int* offs   = hist + NBUCK;
  int* cursor = offs + NBUCK;
  int* gbase  = cursor + NBUCK;
  int* sc     = gbase + NBUCK;                // 256 ints

  int e0 = blockIdx.x * CHUNK;
  int m = N_EDGES - e0; if (m > CHUNK) m = CHUNK;

  for (int i = tid; i < NBUCK; i += 256) hist[i] = 0;
  __syncthreads();

  for (int i = tid; i < m; i += 256)
    atomicAdd(&hist[dst[e0 + i] >> BUCK_SHIFT], 1);
  __syncthreads();

  sc[tid] = (tid < NBUCK) ? hist[tid] : 0;
  __syncthreads();
  for (int ofs = 1; ofs < 256; ofs <<= 1) {
    int t = (tid >= ofs) ? sc[tid - ofs] : 0;
    __syncthreads();
    sc[tid] += t;
    __syncthreads();
  }
  if (tid < NBUCK) {
    int o = tid ? sc[tid - 1] : 0;
    offs[tid] = o;
    cursor[tid] = o;
    gbase[tid] = hist[tid] ? atomicAdd(&bucket_cursor[tid], hist[tid]) : 0;
  }
  __syncthreads();

  for (int i = tid; i < m; i += 256) {
    int2 p = make_int2(src[e0 + i], dst[e0 + i]);
    int pos = atomicAdd(&cursor[p.y >> BUCK_SHIFT], 1);
    stage[pos] = p;
  }
  __syncthreads();

  for (int i = tid; i < m; i += 256) {
    int2 p = stage[i];
    int bd = p.y >> BUCK_SHIFT;
    int gpos = gbase[bd] + (i - offs[bd]);
    if (gpos < SEGCAP) {
      seg[(size_t)bd * SEGCAP + gpos] = p;
    } else {                                // ~never: count + defer to agg ovf fixup
      atomicAdd(&cnt[p.y], 1);
      int o = atomicAdd(ovf_cnt, 1);
      if (o < OVF_CAP) { ovf[2 * o] = p.x; ovf[2 * o + 1] = p.y; }
    }
  }
}

// ---- launch 2: binbuild only ----
__global__ __launch_bounds__(256) void binbuild_kernel(const int2* __restrict__ seg,
                                                       const int* __restrict__ bucket_cursor,
                                                       int* __restrict__ cnt,
                                                       float* __restrict__ dinv,
                                                       int* __restrict__ elist,
                                                       int* __restrict__ ovf_cnt,
                                                       int* __restrict__ ovf) {
  __shared__ int lcnt[BIN_NODES];
  __shared__ int lel[BIN_NODES * ECAP];     // 32 KB
  int tid = threadIdx.x;

  int n0 = blockIdx.x * BIN_NODES;
  int pb = n0 >> BUCK_SHIFT;
  if (tid < BIN_NODES) lcnt[tid] = 0;
  __syncthreads();
  int m = bucket_cursor[pb]; if (m > SEGCAP) m = SEGCAP;
  const int2* s = seg + (size_t)pb * SEGCAP;
  for (int e = tid; e < m; e += 256) {
    int2 p = s[e];
    unsigned ln = (unsigned)(p.y - n0);
    if (ln < (unsigned)BIN_NODES) {
      int pos = atomicAdd(&lcnt[ln], 1);
      if (pos < ECAP) {
        lel[(ln << 6) + pos] = p.x;
      } else {                              // high-degree node: agg ovf fixup
        int o = atomicAdd(ovf_cnt, 1);
        if (o < OVF_CAP) { ovf[2 * o] = p.x; ovf[2 * o + 1] = p.y; }
      }
    }
  }
  __syncthreads();
  if (tid < BIN_NODES) {
    int n = n0 + tid;
    if (n < N_NODES) {
      int tot = cnt[n] + lcnt[tid];          // cnt[n]: pass-1 ovf edges only
      cnt[n] = tot;                          // safe: block owns node range
      dinv[n] = rsqrtf((float)tot + 1.0f);   // fused dinv
    }
  }
  int4* gel = (int4*)(elist + (size_t)n0 * ECAP);
  const int4* lel4 = (const int4*)lel;
  for (int i = tid; i < BIN_NODES * ECAP / 4; i += 256) gel[i] = lel4[i];
}

// ---------------- launch 3: layer-1 aggregation FUSED with layer-2 GEMM ------
// R10: H1 rows are fp8 (128B = 1 line/row -> per-XCD compulsory traffic halves).
// Weighted gather (w = dinv[s]*dinv[d]); accumulate fp32; LDS tile stays bf16
// for the MFMA; epilogue writes H2 = fp8(dinv*(A1@W2)) so agg_pool's gather
// is unweighted AND single-line.
__global__ __launch_bounds__(512) void agg_gemm_kernel(const unsigned* __restrict__ h1,
                                                       const int* __restrict__ elist,
                                                       const int* __restrict__ cnt,
                                                       const float* __restrict__ dinv,
                                                       const float* __restrict__ bias,
                                                       const int* __restrict__ ovf_cnt,
                                                       const int* __restrict__ ovf,
                                                       const unsigned short* __restrict__ Wt2,
                                                       unsigned* __restrict__ H2) {
  __shared__ __align__(16) unsigned short hloc[16 * LDSROW];  // 4.25 KB
  int tid = threadIdx.x;
  int lane = tid & 63;
  int lw = tid >> 6;                         // local wave 0..7
  int hl = lane & 31;
  int n0 = blockIdx.x * 16;
  int nloc = lw * 2 + (lane >> 5);
  int n = n0 + nloc;                         // grid exact: 6250*16 == N_NODES

  float dn = dinv[n];
  int c = cnt[n]; c = (c > ECAP) ? ECAP : c;
  const int* el = elist + (size_t)n * ECAP;

  int   s0 = (hl < c)      ? el[hl]      : n;
  float w0 = (hl < c)      ? dinv[s0] * dn : 0.f;
  int   s1 = (hl + 32 < c) ? el[hl + 32] : n;
  float w1 = (hl + 32 < c) ? dinv[s1] * dn : 0.f;

  int cA = __shfl(c, 0), cB = __shfl(c, 32);
  int cmax = cA > cB ? cA : cB;

  unsigned hv = h1[(size_t)n * 32 + hl];     // self row, feats [hl*4, +4)
  float sf[4]; fp8x4_to_f32(hv, sf);
  float sw = dn * dn;
  float a0 = sw * sf[0], a1 = sw * sf[1], a2 = sw * sf[2], a3 = sw * sf[3];

  int e1 = cmax < 32 ? cmax : 32;
  e1 = (e1 + 7) & ~7;                        // pad: no scalar tail
  for (int j = 0; j < e1; j += 8) {
    unsigned pv[8]; float w[8];
    #pragma unroll
    for (int u = 0; u < 8; ++u) {
      int s = __shfl(s0, j + u, 32);
      w[u] = __shfl(w0, j + u, 32);
      pv[u] = h1[(size_t)s * 32 + hl];
    }
    #pragma unroll
    for (int u = 0; u < 8; ++u) {
      float f[4]; fp8x4_to_f32(pv[u], f);
      a0 = fmaf(w[u], f[0], a0); a1 = fmaf(w[u], f[1], a1);
      a2 = fmaf(w[u], f[2], a2); a3 = fmaf(w[u], f[3], a3);
    }
  }
  if (cmax > 32) {
    int e2 = ((cmax - 32) + 7) & ~7;         // <= 32 since c clamped to ECAP
    for (int j = 0; j < e2; j += 8) {
      unsigned pv[8]; float w[8];
      #pragma unroll
      for (int u = 0; u < 8; ++u) {
        int s = __shfl(s1, j + u, 32);
        w[u] = __shfl(w1, j + u, 32);
        pv[u] = h1[(size_t)s * 32 + hl];
      }
      #pragma unroll
      for (int u = 0; u < 8; ++u) {
        float f[4]; fp8x4_to_f32(pv[u], f);
        a0 = fmaf(w[u], f[0], a0); a1 = fmaf(w[u], f[1], a1);
        a2 = fmaf(w[u], f[2], a2); a3 = fmaf(w[u], f[3], a3);
      }
    }
  }

  int m = *ovf_cnt; if (m > OVF_CAP) m = OVF_CAP;
  for (int p = 0; p < m; ++p) {
    int s = ovf[2 * p], d = ovf[2 * p + 1];
    if (d == n) {
      float w = dinv[s] * dn;
      float f[4]; fp8x4_to_f32(h1[(size_t)s * 32 + hl], f);
      a0 = fmaf(w, f[0], a0); a1 = fmaf(w, f[1], a1);
      a2 = fmaf(w, f[2], a2); a3 = fmaf(w, f[3], a3);
    }
  }

  float4 b4 = ((const float4*)bias)[hl];
  uint2 v;
  v.x = ((unsigned)f2bf(fmaxf(a1 + b4.y, 0.f)) << 16) | f2bf(fmaxf(a0 + b4.x, 0.f));
  v.y = ((unsigned)f2bf(fmaxf(a3 + b4.w, 0.f)) << 16) | f2bf(fmaxf(a2 + b4.z, 0.f));
  *(uint2*)(&hloc[nloc * LDSROW + hl * 4]) = v;
  __syncthreads();

  // ---- phase 2: gemm2 tile. wave lw -> output feats [lw*16, lw*16+16) ----
  int q = lane >> 4, r = lane & 15;
  int node = n0 + r;
  float dvr = dinv[node];                    // for P2 pre-scale (load early)
  f32x4 acc = (f32x4){0.f, 0.f, 0.f, 0.f};
  #pragma unroll
  for (int s = 0; s < 4; ++s) {
    int k0 = s * 32 + q * 8;
    bf16x8 xf = *(const bf16x8*)(&hloc[r * LDSROW + k0]);
    bf16x8 wf = *(const bf16x8*)(Wt2 + (size_t)(lw * 16 + r) * NFEAT + k0);
    acc = __builtin_amdgcn_mfma_f32_16x16x32_bf16(wf, xf, acc, 0, 0, 0);
  }
  // feats [lw*16+q*4, +4) as 4x fp8
  H2[(size_t)node * 32 + lw * 4 + q] =
      f32x4_to_fp8(dvr * acc[0], dvr * acc[1], dvr * acc[2], dvr * acc[3]);
}

// ---------------- launch 4: layer-2 aggregation + FUSED POOL ----------------
// H2 holds PRE-SCALED fp8 rows P2 -> unweighted single-line gather.
__global__ __launch_bounds__(256) void agg_pool_kernel(const unsigned* __restrict__ h2,
                                                       const int* __restrict__ elist,
                                                       const int* __restrict__ cnt,
                                                       const float* __restrict__ dinv,
                                                       const float* __restrict__ bias,
                                                       const int* __restrict__ ovf_cnt,
                                                       const int* __restrict__ ovf,
                                                       const int* __restrict__ batch,
                                                       float* __restrict__ gsum) {
  __shared__ float lds[8][NFEAT];            // 4 KB
  int tid = threadIdx.x;
  int wid = (blockIdx.x * 256 + tid) >> 6;
  int lane = tid & 63;
  int hl = lane & 31;
  int n = wid * 2 + (lane >> 5);             // grid covers exactly N_NODES
  int n0 = blockIdx.x * 8;

  float dn = dinv[n];
  int c = cnt[n]; c = (c > ECAP) ? ECAP : c;
  const int* el = elist + (size_t)n * ECAP;

  int s0 = (hl < c)      ? el[hl]      : n;
  int s1 = (hl + 32 < c) ? el[hl + 32] : n;

  int cA = __shfl(c, 0), cB = __shfl(c, 32);
  int cmax = cA > cB ? cA : cB;

  float sf[4]; fp8x4_to_f32(h2[(size_t)n * 32 + hl], sf);  // self, weight 1
  float a0 = sf[0], a1 = sf[1], a2 = sf[2], a3 = sf[3];

  int e1 = cmax < 32 ? cmax : 32;
  e1 = (e1 + 7) & ~7;                        // pad: no scalar tail
  for (int j = 0; j < e1; j += 8) {
    unsigned pv[8];
    #pragma unroll
    for (int u = 0; u < 8; ++u) {
      int s = __shfl(s0, j + u, 32);
      pv[u] = h2[(size_t)s * 32 + hl];
    }
    #pragma unroll
    for (int u = 0; u < 8; ++u) {
      if (j + u < c) {                       // mask padding (c uniform/half-wave)
        float f[4]; fp8x4_to_f32(pv[u], f);
        a0 += f[0]; a1 += f[1]; a2 += f[2]; a3 += f[3];
      }
    }
  }
  if (cmax > 32) {
    int e2 = 32 + (((cmax - 32) + 7) & ~7);
    for (int j = 32; j < e2; j += 8) {
      unsigned pv[8];
      #pragma unroll
      for (int u = 0; u < 8; ++u) {
        int s = __shfl(s1, j - 32 + u, 32);
        pv[u] = h2[(size_t)s * 32 + hl];
      }
      #pragma unroll
      for (int u = 0; u < 8; ++u) {
        if (j + u < c) {
          float f[4]; fp8x4_to_f32(pv[u], f);
          a0 += f[0]; a1 += f[1]; a2 += f[2]; a3 += f[3];
        }
      }
    }
  }

  int m = *ovf_cnt; if (m > OVF_CAP) m = OVF_CAP;
  for (int p = 0; p < m; ++p) {
    int s = ovf[2 * p], d = ovf[2 * p + 1];
    if (d == n) {
      float f[4]; fp8x4_to_f32(h2[(size_t)s * 32 + hl], f);
      a0 += f[0]; a1 += f[1]; a2 += f[2]; a3 += f[3];
    }
  }

  float4 b4 = ((const float4*)bias)[hl];
  int nloc = n - n0;
  lds[nloc][hl * 4 + 0] = fmaxf(fmaf(dn, a0, b4.x), 0.f);
  lds[nloc][hl * 4 + 1] = fmaxf(fmaf(dn, a1, b4.y), 0.f);
  lds[nloc][hl * 4 + 2] = fmaxf(fmaf(dn, a2, b4.z), 0.f);
  lds[nloc][hl * 4 + 3] = fmaxf(fmaf(dn, a3, b4.w), 0.f);
  __syncthreads();

  if (tid < NFEAT) {                         // thread t = feature t
    float sum = 0.f;
    int cur = batch[n0];
    #pragma unroll
    for (int i = 0; i < 8; ++i) {
      int b = batch[n0 + i];
      if (b != cur) {
        atomicAdd(&gsum[cur * NFEAT + tid], sum);
        sum = 0.f; cur = b;
      }
      sum += lds[i][tid];
    }
    atomicAdd(&gsum[cur * NFEAT + tid], sum);
  }
}

// ---------------- MLP head (graph-count binary search fused in) ----------------
__global__ __launch_bounds__(128) void mlp_kernel(const float* __restrict__ gsum,
                                                  const int* __restrict__ batch,
                                                  const float* __restrict__ Wl1,
                                                  const float* __restrict__ bl1,
                                                  const float* __restrict__ Wl2,
                                                  const float* __restrict__ bl2,
                                                  float* __restrict__ out) {
  __shared__ float gr[NFEAT];
  __shared__ float t1[NFEAT];
  __shared__ float sinv;
  int g = blockIdx.x, t = threadIdx.x;
  if (t == 0) {
    int lo = 0, hi = N_NODES;
    while (lo < hi) { int mid = (lo + hi) >> 1; if (batch[mid] < g) lo = mid + 1; else hi = mid; }
    int lo2 = lo, hi2 = N_NODES;
    while (lo2 < hi2) { int mid = (lo2 + hi2) >> 1; if (batch[mid] < g + 1) lo2 = mid + 1; else hi2 = mid; }
    sinv = 1.0f / fmaxf((float)(lo2 - lo), 1.0f);
  }
  __syncthreads();
  gr[t] = gsum[g * NFEAT + t] * sinv;
  __syncthreads();
  float acc = bl1[t];
  for (int k = 0; k < NFEAT; ++k) acc = fmaf(gr[k], Wl1[k * NFEAT + t], acc);
  t1[t] = fmaxf(acc, 0.f);
  __syncthreads();
  if (t < NACT) {
    float a2 = bl2[t];
    for (int k = 0; k < NFEAT; ++k) a2 = fmaf(t1[k], Wl2[k * NACT + t], a2);
    out[g * NACT + t] = a2;
  }
}

extern "C" void kernel_launch(void* const* d_in, const int* in_sizes, int n_in,
                              void* d_out, int out_size, void* d_ws, size_t ws_size,
                              hipStream_t stream) {
  const float* x    = (const float*)d_in[0];
  const int*   ei   = (const int*)d_in[1];
  const int*   batch= (const int*)d_in[2];
  const float* W1   = (const float*)d_in[3];
  const float* b1   = (const float*)d_in[4];
  const float* W2   = (const float*)d_in[5];
  const float* b2   = (const float*)d_in[6];
  const float* Wl1  = (const float*)d_in[7];
  const float* bl1  = (const float*)d_in[8];
  const float* Wl2  = (const float*)d_in[9];
  const float* bl2  = (const float*)d_in[10];
  float* out = (float*)d_out;

  const int* srcp = ei;            // edge_index[0]
  const int* dstp = ei + N_EDGES;  // edge_index[1]

  char* base = (char*)d_ws;
  size_t off = 0;
  auto alloc = [&](size_t bytes) -> void* {
    void* p = base + off;
    off += (bytes + 511) & ~(size_t)511;
    return p;
  };
  int*   cnt     = (int*)alloc((size_t)N_NODES * 4);
  int*   ovfc    = (int*)alloc(4);
  float* gsum    = (float*)alloc((size_t)NGRAPH * NFEAT * 4);
  int*   bucket_cursor = (int*)alloc((size_t)NBUCK * 4);
  size_t zspan   = off;  // everything above must start zeroed
  float* dinv    = (float*)alloc((size_t)N_NODES * 4);
  int*   elist   = (int*)alloc((size_t)NBLK2 * BIN_NODES * ECAP * 4); // padded
  int*   ovf     = (int*)alloc((size_t)OVF_CAP * 2 * 4);
  int2*  seg     = (int2*)alloc((size_t)NBUCK * SEGCAP * 8);          // 16 MB
  unsigned short* Wt2 = (unsigned short*)alloc((size_t)NFEAT * NFEAT * 2);
  unsigned* H1 = (unsigned*)alloc((size_t)N_NODES * NFEAT);  // fp8 rows (128B)
  unsigned* H2 = (unsigned*)alloc((size_t)N_NODES * NFEAT);  // fp8 P2 rows

  hipMemsetAsync(d_ws, 0, zspan, stream);

  const int AB = (N_NODES + 7) / 8;       // 12500 agg_pool blocks (8 nodes/block)
  const int FB = N_NODES / 16;            // 6250 fused agg+gemm blocks (16 nodes)

  // L1: edge partition UNION Wt2 transpose UNION layer-1 GEMM (all independent)
  edgepart_wt_gemm1_kernel<<<NBLK1 + WT2BLK + GB, 256, 0, stream>>>(
      srcp, dstp, bucket_cursor, seg, cnt, ovfc, ovf, W1, W2, Wt2, x, H1);
  // L2: elist build (dep on L1 edgepart)
  binbuild_kernel<<<NBLK2, 256, 0, stream>>>(
      seg, bucket_cursor, cnt, dinv, elist, ovfc, ovf);
  // L3: layer-1 aggregation (weighted, fp8 rows) FUSED with layer-2 GEMM
  agg_gemm_kernel<<<FB, 512, 0, stream>>>(H1, elist, cnt, dinv, b1,
                                          ovfc, ovf, Wt2, H2);
  // L4: layer-2 aggregation (unweighted, pre-scaled fp8) + fused pool
  agg_pool_kernel<<<AB, 256, 0, stream>>>(H2, elist, cnt, dinv, b2,
                                          ovfc, ovf, batch, gsum);
  // L5: head
  mlp_kernel<<<NGRAPH, 128, 0, stream>>>(gsum, batch, Wl1, bl1, Wl2, bl2, out);
}